// Round 2
// baseline (111.671 us; speedup 1.0000x reference)
//
#include <hip/hip_runtime.h>

#define IMG_H 512
#define IMG_W 512
#define NCH   24   // 8 batches * 3 channels

__device__ __forceinline__ double exs(int r2) {
    // exp(-r2/2); compile-time folded under full unroll (r2 is a constant)
    switch (r2) {
        case 0: return 1.0;
        case 1: return 0.60653065971263342;
        case 2: return 0.36787944117144233;
        case 4: return 0.13533528323661270;
        case 5: return 0.08208499862389880;
        case 8: return 0.01831563888873418;
    }
    return 0.0;
}

// sum of all 25 spatial weights (double precision)
#define SSUM 6.16892408102888092
// -50 / ln(2) : intensity exponent in log2 domain (sigma_int = 0.1)
#define NEG50_LOG2E -72.134752044448169f
// -0.5 / ln(2) per unit r2 : spatial weight in log2 domain
#define NEGHALF_LOG2E -0.72134752044448169f

__global__ __launch_bounds__(256) void aa_kernel(const float* __restrict__ in,
                                                 float* __restrict__ out) {
    const int gid = blockIdx.x * 256 + threadIdx.x;
    const int ch  = gid >> 16;            // 65536 threads (=262144 px /4) per channel
    const int rem = gid & 65535;
    const int y   = rem >> 7;             // 128 4-pixel groups per row -> y in 0..511
    const int x0  = (rem & 127) << 2;

    const float* __restrict__ img = in  + ch * (IMG_H * IMG_W);
    float*       __restrict__ op  = out + ch * (IMG_H * IMG_W);

    float res[4];

    const bool interior = (y >= 2) & (y < IMG_H - 2) & (x0 >= 4) & (x0 <= IMG_W - 8);

    if (interior) {
        // 5x8 register window covering taps for 4 consecutive output pixels
        float v[5][8];
        #pragma unroll
        for (int r = 0; r < 5; ++r) {
            const float* row = img + (y - 2 + r) * IMG_W + (x0 - 2);
            #pragma unroll
            for (int c = 0; c < 8; ++c) v[r][c] = row[c];
        }
        #pragma unroll
        for (int p = 0; p < 4; ++p) {
            const float ctr = v[2][2 + p];
            float g = 0.f, wsum = 0.f, bsum = 0.f;
            #pragma unroll
            for (int i = 0; i < 5; ++i) {
                #pragma unroll
                for (int j = 0; j < 5; ++j) {
                    const int r2 = (i - 2) * (i - 2) + (j - 2) * (j - 2);
                    const float gk  = (float)(exs(r2) / SSUM);
                    const float lsw = NEGHALF_LOG2E * (float)r2;
                    const float val = v[i][p + j];
                    const float d   = val - ctr;
                    const float w   = exp2f(fmaf(d * d, NEG50_LOG2E, lsw));
                    wsum += w;
                    bsum = fmaf(w, val, bsum);
                    g    = fmaf(gk, val, g);
                }
            }
            res[p] = 0.6f * g + 0.4f * (bsum / (wsum + 1e-8f));
        }
    } else {
        // border: reflect padding for bilateral, zero padding for gaussian
        #pragma unroll
        for (int p = 0; p < 4; ++p) {
            const int x = x0 + p;
            const float ctr = img[y * IMG_W + x];
            float g = 0.f, wsum = 0.f, bsum = 0.f;
            #pragma unroll
            for (int i = 0; i < 5; ++i) {
                const int yy = y + i - 2;
                const bool yin = (yy >= 0) & (yy < IMG_H);
                const int ry = (yy < 0) ? -yy : ((yy >= IMG_H) ? 2 * IMG_H - 2 - yy : yy);
                #pragma unroll
                for (int j = 0; j < 5; ++j) {
                    const int r2 = (i - 2) * (i - 2) + (j - 2) * (j - 2);
                    const float gk  = (float)(exs(r2) / SSUM);
                    const float lsw = NEGHALF_LOG2E * (float)r2;
                    const int xx = x + j - 2;
                    const bool xin = (xx >= 0) & (xx < IMG_W);
                    const int rx = (xx < 0) ? -xx : ((xx >= IMG_W) ? 2 * IMG_W - 2 - xx : xx);
                    const float val = img[ry * IMG_W + rx];
                    const float d   = val - ctr;
                    const float w   = exp2f(fmaf(d * d, NEG50_LOG2E, lsw));
                    wsum += w;
                    bsum = fmaf(w, val, bsum);
                    if (yin & xin) g = fmaf(gk, val, g);
                }
            }
            res[p] = 0.6f * g + 0.4f * (bsum / (wsum + 1e-8f));
        }
    }

    float4* o4 = (float4*)(op + y * IMG_W + x0);
    *o4 = make_float4(res[0], res[1], res[2], res[3]);
}

extern "C" void kernel_launch(void* const* d_in, const int* in_sizes, int n_in,
                              void* d_out, int out_size, void* d_ws, size_t ws_size,
                              hipStream_t stream) {
    const float* img = (const float*)d_in[0];
    float* out = (float*)d_out;
    // 24 channels * 262144 pixels / 4 px-per-thread / 256 threads-per-block
    const int blocks = (NCH * IMG_H * IMG_W) / 4 / 256;
    aa_kernel<<<blocks, 256, 0, stream>>>(img, out);
}

// Round 3
// 39.364 us; speedup vs baseline: 2.8369x; 2.8369x over previous
//
#include <hip/hip_runtime.h>

#define IMG_H 512
#define IMG_W 512
#define NCH   24   // 8 batches * 3 channels

#if __has_builtin(__builtin_amdgcn_exp2f)
#define EXP2(x) __builtin_amdgcn_exp2f(x)
#else
#define EXP2(x) exp2f(x)
#endif
#if __has_builtin(__builtin_amdgcn_rcpf)
#define RCP(x) __builtin_amdgcn_rcpf(x)
#else
#define RCP(x) (1.0f/(x))
#endif

__device__ __forceinline__ double exs(int r2) {
    // exp(-r2/2); compile-time folded under full unroll (r2 is a constant)
    switch (r2) {
        case 0: return 1.0;
        case 1: return 0.60653065971263342;
        case 2: return 0.36787944117144233;
        case 4: return 0.13533528323661270;
        case 5: return 0.08208499862389880;
        case 8: return 0.01831563888873418;
    }
    return 0.0;
}

// sum of all 25 spatial weights (double precision)
#define SSUM 6.16892408102888092
// -50 / ln(2) : intensity exponent in log2 domain (sigma_int = 0.1)
#define NEG50_LOG2E -72.134752044448169f
// -0.5 / ln(2) per unit r2 : spatial weight in log2 domain
#define NEGHALF_LOG2E -0.72134752044448169f

// Interior geometry: x0 in {4..504} (126 groups), y in {2..509} (508 rows)
#define XG_INT 126
#define YR_INT 508
#define PER_CH_INT (XG_INT * YR_INT)      // 64008
#define N_INT (PER_CH_INT * NCH)          // 1,536,192 (= 24,003 waves exactly)
// Border geometry: 4 full rows (y=0,1,510,511) * 128 groups + 508 rows * 2 edge groups
#define PER_CH_B (4 * 128 + YR_INT * 2)   // 1528
#define N_B (PER_CH_B * NCH)              // 36,672
// N_INT + N_B = 1,572,864 = 6144 blocks * 256 exactly

__global__ __launch_bounds__(256) void aa_kernel(const float* __restrict__ in,
                                                 float* __restrict__ out) {
    const int gid = blockIdx.x * 256 + threadIdx.x;

    if (gid < N_INT) {
        // ------------- interior: uniform fast path, no bounds logic -------------
        const int ch  = gid / PER_CH_INT;
        const int rem = gid - ch * PER_CH_INT;
        const int yy  = rem / XG_INT;
        const int y   = 2 + yy;
        const int x0  = 4 + (rem - yy * XG_INT) * 4;

        const float* __restrict__ img = in + ch * (IMG_H * IMG_W);

        // 5x8 register window: rows y-2..y+2, cols x0-2..x0+5 (8B-aligned float2s)
        float v[5][8];
        const float* base = img + (y - 2) * IMG_W + (x0 - 2);
        #pragma unroll
        for (int r = 0; r < 5; ++r) {
            const float2* rp = (const float2*)(base + r * IMG_W);
            float2 a = rp[0], b = rp[1], c = rp[2], d = rp[3];
            v[r][0] = a.x; v[r][1] = a.y; v[r][2] = b.x; v[r][3] = b.y;
            v[r][4] = c.x; v[r][5] = c.y; v[r][6] = d.x; v[r][7] = d.y;
        }

        float res[4];
        #pragma unroll
        for (int p = 0; p < 4; ++p) {
            const float ctr = v[2][2 + p];
            float g = 0.f, wsum = 0.f, bsum = 0.f;
            #pragma unroll
            for (int i = 0; i < 5; ++i) {
                #pragma unroll
                for (int j = 0; j < 5; ++j) {
                    const int r2 = (i - 2) * (i - 2) + (j - 2) * (j - 2);
                    const float gk  = (float)(exs(r2) / SSUM);
                    const float lsw = NEGHALF_LOG2E * (float)r2;
                    const float val = v[i][p + j];
                    const float d   = val - ctr;
                    const float w   = EXP2(fmaf(d * d, NEG50_LOG2E, lsw));
                    wsum += w;
                    bsum = fmaf(w, val, bsum);
                    g    = fmaf(gk, val, g);
                }
            }
            res[p] = 0.6f * g + 0.4f * (bsum * RCP(wsum + 1e-8f));
        }

        float4* o4 = (float4*)(out + ch * (IMG_H * IMG_W) + y * IMG_W + x0);
        *o4 = make_float4(res[0], res[1], res[2], res[3]);
    } else {
        // ------------- border: reflect (bilateral) + zero-pad (gaussian) -------------
        const int bi = gid - N_INT;               // grid sized exactly, no guard needed
        const int ch = bi / PER_CH_B;
        const int r  = bi - ch * PER_CH_B;
        int y, x0;
        if (r < 512) {
            const int q = r >> 7;                 // 0..3 -> rows {0,1,510,511}
            y  = (q < 2) ? q : q + 508;
            x0 = (r & 127) << 2;
        } else {
            const int r2_ = r - 512;
            y  = 2 + (r2_ >> 1);
            x0 = (r2_ & 1) ? (IMG_W - 4) : 0;
        }

        const float* __restrict__ img = in + ch * (IMG_H * IMG_W);

        float res[4];
        #pragma unroll
        for (int p = 0; p < 4; ++p) {
            const int x = x0 + p;
            const float ctr = img[y * IMG_W + x];
            float g = 0.f, wsum = 0.f, bsum = 0.f;
            #pragma unroll
            for (int i = 0; i < 5; ++i) {
                const int yy = y + i - 2;
                const bool yin = (yy >= 0) & (yy < IMG_H);
                const int ry = (yy < 0) ? -yy : ((yy >= IMG_H) ? 2 * IMG_H - 2 - yy : yy);
                #pragma unroll
                for (int j = 0; j < 5; ++j) {
                    const int r2 = (i - 2) * (i - 2) + (j - 2) * (j - 2);
                    const float gk  = (float)(exs(r2) / SSUM);
                    const float lsw = NEGHALF_LOG2E * (float)r2;
                    const int xx = x + j - 2;
                    const bool xin = (xx >= 0) & (xx < IMG_W);
                    const int rx = (xx < 0) ? -xx : ((xx >= IMG_W) ? 2 * IMG_W - 2 - xx : xx);
                    const float val = img[ry * IMG_W + rx];
                    const float d   = val - ctr;
                    const float w   = EXP2(fmaf(d * d, NEG50_LOG2E, lsw));
                    wsum += w;
                    bsum = fmaf(w, val, bsum);
                    if (yin & xin) g = fmaf(gk, val, g);
                }
            }
            res[p] = 0.6f * g + 0.4f * (bsum * RCP(wsum + 1e-8f));
        }

        float4* o4 = (float4*)(out + ch * (IMG_H * IMG_W) + y * IMG_W + x0);
        *o4 = make_float4(res[0], res[1], res[2], res[3]);
    }
}

extern "C" void kernel_launch(void* const* d_in, const int* in_sizes, int n_in,
                              void* d_out, int out_size, void* d_ws, size_t ws_size,
                              hipStream_t stream) {
    const float* img = (const float*)d_in[0];
    float* out = (float*)d_out;
    const int total = N_INT + N_B;                // 1,572,864
    aa_kernel<<<total / 256, 256, 0, stream>>>(img, out);
}

// Round 4
// 39.112 us; speedup vs baseline: 2.8551x; 1.0064x over previous
//
#include <hip/hip_runtime.h>

#define IMG_H 512
#define IMG_W 512
#define NCH   24   // 8 batches * 3 channels

typedef float v2f __attribute__((ext_vector_type(2)));

__device__ __forceinline__ float fexp2(float x) {
#if __has_builtin(__builtin_amdgcn_exp2f)
    return __builtin_amdgcn_exp2f(x);
#else
    float r; asm("v_exp_f32 %0, %1" : "=v"(r) : "v"(x)); return r;
#endif
}
__device__ __forceinline__ float frcp(float x) {
#if __has_builtin(__builtin_amdgcn_rcpf)
    return __builtin_amdgcn_rcpf(x);
#else
    float r; asm("v_rcp_f32 %0, %1" : "=v"(r) : "v"(x)); return r;
#endif
}
__device__ __forceinline__ v2f fma2(v2f a, v2f b, v2f c) {
#if __has_builtin(__builtin_elementwise_fma)
    return __builtin_elementwise_fma(a, b, c);
#else
    v2f r; r.x = fmaf(a.x, b.x, c.x); r.y = fmaf(a.y, b.y, c.y); return r;
#endif
}
__device__ __forceinline__ v2f mk2(float a, float b) { v2f r; r.x = a; r.y = b; return r; }

// exp(-r2/2) (double, folded at compile time)
__device__ __forceinline__ constexpr double exs(int r2) {
    return (r2 == 0) ? 1.0
         : (r2 == 1) ? 0.60653065971263342
         : (r2 == 2) ? 0.36787944117144233
         : (r2 == 4) ? 0.13533528323661270
         : (r2 == 5) ? 0.08208499862389880
         : (r2 == 8) ? 0.01831563888873418 : 0.0;
}
#define SSUM 6.16892408102888092
// gaussian kernel coefficient for tap class r2
__device__ __forceinline__ constexpr float gkc(int r2) { return (float)(exs(r2) / SSUM); }
// -50/ln2 (intensity) and -0.5/ln2 (spatial, per unit r2), log2 domain
#define NEG50  -72.134752044448169f
#define LG     -0.72134752044448169f

// Interior geometry: x0 in {4..504} (126 groups), y in {2..509} (508 rows)
#define XG_INT 126
#define YR_INT 508
#define PER_CH_INT (XG_INT * YR_INT)      // 64008
#define N_INT (PER_CH_INT * NCH)          // 1,536,192 (= 24,003 waves exactly)
#define PER_CH_B (4 * 128 + YR_INT * 2)   // 1528
#define N_B (PER_CH_B * NCH)              // 36,672
// N_INT + N_B = 1,572,864 = 6144 blocks * 256

__global__ __launch_bounds__(256) void aa_kernel(const float* __restrict__ in,
                                                 float* __restrict__ out) {
    const int gid = blockIdx.x * 256 + threadIdx.x;

    if (gid < N_INT) {
        // ---------------- interior: packed-fp32 fast path ----------------
        const int ch  = gid / PER_CH_INT;
        const int rem = gid - ch * PER_CH_INT;
        const int yy  = rem / XG_INT;
        const int y   = 2 + yy;
        const int x0  = 4 + (rem - yy * XG_INT) * 4;

        const float* __restrict__ img = in + ch * (IMG_H * IMG_W);
        const float* base = img + (y - 2) * IMG_W + (x0 - 2);

        // 5x8 window; rows (y-2,y-1) packed in A, (y,y+1) in B, y+2 scalar S
        float r0[8], r1[8], r2r[8], r3[8], S[8];
        #pragma unroll
        for (int c = 0; c < 8; c += 2) {
            float2 t0 = *(const float2*)(base + 0 * IMG_W + c);
            float2 t1 = *(const float2*)(base + 1 * IMG_W + c);
            float2 t2 = *(const float2*)(base + 2 * IMG_W + c);
            float2 t3 = *(const float2*)(base + 3 * IMG_W + c);
            float2 t4 = *(const float2*)(base + 4 * IMG_W + c);
            r0[c] = t0.x; r0[c + 1] = t0.y;
            r1[c] = t1.x; r1[c + 1] = t1.y;
            r2r[c] = t2.x; r2r[c + 1] = t2.y;
            r3[c] = t3.x; r3[c + 1] = t3.y;
            S[c] = t4.x; S[c + 1] = t4.y;
        }
        v2f A[8], B[8];
        #pragma unroll
        for (int c = 0; c < 8; ++c) { A[c] = mk2(r0[c], r1[c]); B[c] = mk2(r2r[c], r3[c]); }

        const v2f n50 = mk2(NEG50, NEG50);
        float res[4];
        #pragma unroll
        for (int p = 0; p < 4; ++p) {
            const float ctr = B[2 + p].x;
            const v2f ctr2 = mk2(ctr, ctr);
            v2f w2 = mk2(0.f, 0.f), b2 = w2, g2 = w2;
            float ws_ = 0.f, bs_ = 0.f, gs_ = 0.f;
            #pragma unroll
            for (int j = 0; j < 5; ++j) {
                const int dj2 = (j - 2) * (j - 2);
                const v2f lswA = mk2(LG * (4 + dj2), LG * (1 + dj2));
                const v2f lswB = mk2(LG * (0 + dj2), LG * (1 + dj2));
                const v2f gkA  = mk2(gkc(4 + dj2), gkc(1 + dj2));
                const v2f gkB  = mk2(gkc(0 + dj2), gkc(1 + dj2));
                const float lswS = LG * (4 + dj2);
                const float gkS  = gkc(4 + dj2);

                const v2f a = A[p + j], b = B[p + j];
                const float s = S[p + j];

                v2f dA = a - ctr2, dB = b - ctr2;
                float dS = s - ctr;
                v2f argA = fma2(dA * dA, n50, lswA);
                v2f argB = fma2(dB * dB, n50, lswB);
                float argS = fmaf(dS * dS, NEG50, lswS);
                v2f wA, wB;
                wA.x = fexp2(argA.x); wA.y = fexp2(argA.y);
                wB.x = fexp2(argB.x); wB.y = fexp2(argB.y);
                float wS = fexp2(argS);

                w2 += wA; w2 += wB; ws_ += wS;
                b2 = fma2(wA, a, b2); b2 = fma2(wB, b, b2); bs_ = fmaf(wS, s, bs_);
                g2 = fma2(gkA, a, g2); g2 = fma2(gkB, b, g2); gs_ = fmaf(gkS, s, gs_);
            }
            const float wsum = w2.x + w2.y + ws_;
            const float bsum = b2.x + b2.y + bs_;
            const float g    = g2.x + g2.y + gs_;
            res[p] = fmaf(0.6f, g, 0.4f * (bsum * frcp(wsum + 1e-8f)));
        }

        float4* o4 = (float4*)(out + ch * (IMG_H * IMG_W) + y * IMG_W + x0);
        *o4 = make_float4(res[0], res[1], res[2], res[3]);
    } else {
        // ------------- border: reflect (bilateral) + zero-pad (gaussian) -------------
        const int bi = gid - N_INT;
        const int ch = bi / PER_CH_B;
        const int r  = bi - ch * PER_CH_B;
        int y, x0;
        if (r < 512) {
            const int q = r >> 7;                 // 0..3 -> rows {0,1,510,511}
            y  = (q < 2) ? q : q + 508;
            x0 = (r & 127) << 2;
        } else {
            const int r2_ = r - 512;
            y  = 2 + (r2_ >> 1);
            x0 = (r2_ & 1) ? (IMG_W - 4) : 0;
        }

        const float* __restrict__ img = in + ch * (IMG_H * IMG_W);

        float res[4];
        #pragma unroll
        for (int p = 0; p < 4; ++p) {
            const int x = x0 + p;
            const float ctr = img[y * IMG_W + x];
            float g = 0.f, wsum = 0.f, bsum = 0.f;
            #pragma unroll
            for (int i = 0; i < 5; ++i) {
                const int yy = y + i - 2;
                const bool yin = (yy >= 0) & (yy < IMG_H);
                const int ry = (yy < 0) ? -yy : ((yy >= IMG_H) ? 2 * IMG_H - 2 - yy : yy);
                #pragma unroll
                for (int j = 0; j < 5; ++j) {
                    const int r2 = (i - 2) * (i - 2) + (j - 2) * (j - 2);
                    const float gk  = gkc(r2);
                    const float lsw = LG * (float)r2;
                    const int xx = x + j - 2;
                    const bool xin = (xx >= 0) & (xx < IMG_W);
                    const int rx = (xx < 0) ? -xx : ((xx >= IMG_W) ? 2 * IMG_W - 2 - xx : xx);
                    const float val = img[ry * IMG_W + rx];
                    const float d   = val - ctr;
                    const float w   = fexp2(fmaf(d * d, NEG50, lsw));
                    wsum += w;
                    bsum = fmaf(w, val, bsum);
                    if (yin & xin) g = fmaf(gk, val, g);
                }
            }
            res[p] = fmaf(0.6f, g, 0.4f * (bsum * frcp(wsum + 1e-8f)));
        }

        float4* o4 = (float4*)(out + ch * (IMG_H * IMG_W) + y * IMG_W + x0);
        *o4 = make_float4(res[0], res[1], res[2], res[3]);
    }
}

extern "C" void kernel_launch(void* const* d_in, const int* in_sizes, int n_in,
                              void* d_out, int out_size, void* d_ws, size_t ws_size,
                              hipStream_t stream) {
    const float* img = (const float*)d_in[0];
    float* out = (float*)d_out;
    const int total = N_INT + N_B;                // 1,572,864
    aa_kernel<<<total / 256, 256, 0, stream>>>(img, out);
}